// Round 2
// baseline (156.208 us; speedup 1.0000x reference)
//
#include <hip/hip_runtime.h>

#define BB   16
#define HH   74
#define WW   74
#define DD   768
#define NHh  8
#define NOo  16
#define NREL 117

// K1: ROI mean via direct box summation.
// grid = B*(NH+NO) = 384 blocks, 256 threads.
// Output X: 384 rows x 768 (rows 0..127 = hf[b*8+h], rows 128..383 = of[b*16+o]).
__global__ __launch_bounds__(256) void roi_kernel(const float* __restrict__ feats,
                                                  const int* __restrict__ hboxes,
                                                  const int* __restrict__ oboxes,
                                                  float* __restrict__ X)
{
    int blk = blockIdx.x;
    int b = blk / (NHh + NOo);
    int i = blk % (NHh + NOo);
    const int* box;
    float* outRow;
    if (i < NHh) {
        box = hboxes + (b * NHh + i) * 4;
        outRow = X + (b * NHh + i) * DD;
    } else {
        int o = i - NHh;
        box = oboxes + (b * NOo + o) * 4;
        outRow = X + (128 + b * NOo + o) * DD;
    }
    int x1 = box[0], y1 = box[1], x2 = box[2], y2 = box[3];
    float inv_area = 1.0f / (float)((y2 - y1) * (x2 - x1));
    int t = threadIdx.x;
    float a0 = 0.f, a1 = 0.f, a2 = 0.f;
    for (int y = y1; y < y2; ++y) {
        const float* rowp = feats + (size_t)((b * HH + y) * WW) * DD;
        for (int x = x1; x < x2; ++x) {
            const float* p = rowp + (size_t)x * DD;
            a0 += p[t];
            a1 += p[t + 256];
            a2 += p[t + 512];
        }
    }
    outRow[t]       = a0 * inv_area;
    outRow[t + 256] = a1 * inv_area;
    outRow[t + 512] = a2 * inv_area;
}

// K2: AB[r, n] = X[r, :] @ W1half, where rows <128 use W1[0:768,:], rows >=128
// use W1[768:1536,:].  4 rows per block (blocks never straddle row 128).
// grid = 96 blocks, 256 threads.
__global__ __launch_bounds__(256) void gemm1_kernel(const float* __restrict__ X,
                                                    const float* __restrict__ W1,
                                                    float* __restrict__ AB)
{
    __shared__ float xs[4][768];
    int r0 = blockIdx.x * 4;
    int t = threadIdx.x;
    for (int idx = t; idx < 4 * 768; idx += 256) {
        int r = idx / 768;
        int k = idx - r * 768;
        xs[r][k] = X[(r0 + r) * 768 + k];
    }
    __syncthreads();
    const float* Wp = W1 + ((r0 < 128) ? 0 : (size_t)768 * 512);
    float acc[4][2] = {};
    for (int k = 0; k < 768; ++k) {
        float w0 = Wp[(size_t)k * 512 + t];
        float w1 = Wp[(size_t)k * 512 + t + 256];
#pragma unroll
        for (int r = 0; r < 4; ++r) {
            float xv = xs[r][k];
            acc[r][0] = fmaf(xv, w0, acc[r][0]);
            acc[r][1] = fmaf(xv, w1, acc[r][1]);
        }
    }
    for (int r = 0; r < 4; ++r) {
        AB[(r0 + r) * 512 + t]       = acc[r][0];
        AB[(r0 + r) * 512 + t + 256] = acc[r][1];
    }
}

// K3: fused pair-combine + layer2 + layer3.
// 8 pair-rows per block; grid = 2048/8 = 256 blocks, 256 threads.
__global__ __launch_bounds__(256) void mlp_kernel(const float* __restrict__ AB,
                                                  const float* __restrict__ b1,
                                                  const float* __restrict__ W2,
                                                  const float* __restrict__ b2,
                                                  const float* __restrict__ W3,
                                                  const float* __restrict__ b3,
                                                  float* __restrict__ out)
{
    __shared__ float h1[8][512];
    __shared__ float h2[8][256];
    int p0 = blockIdx.x * 8;
    int t = threadIdx.x;

    // phase 1: h1 = relu(A_row + B_row + b1)
    for (int idx = t; idx < 8 * 512; idx += 256) {
        int r = idx >> 9;
        int k = idx & 511;
        int p = p0 + r;
        int rowA = p >> 4;                          // b*8 + h
        int rowB = 128 + (p >> 7) * 16 + (p & 15);  // 128 + b*16 + o
        float v = AB[rowA * 512 + k] + AB[rowB * 512 + k] + b1[k];
        h1[r][k] = v > 0.f ? v : 0.f;
    }
    __syncthreads();

    // phase 2: h2 = relu(h1 @ W2 + b2), thread t owns column j = t
    {
        float acc[8] = {};
        for (int k = 0; k < 512; ++k) {
            float w = W2[(size_t)k * 256 + t];
#pragma unroll
            for (int r = 0; r < 8; ++r) acc[r] = fmaf(h1[r][k], w, acc[r]);
        }
        float bb = b2[t];
#pragma unroll
        for (int r = 0; r < 8; ++r) {
            float v = acc[r] + bb;
            h2[r][t] = v > 0.f ? v : 0.f;
        }
    }
    __syncthreads();

    // phase 3: out = h2 @ W3 + b3  (8 rows x 117 outputs = 936)
    for (int i = 0; i < 4; ++i) {
        int pidx = t + i * 256;
        if (pidx < 8 * NREL) {
            int r = pidx / NREL;
            int o = pidx - r * NREL;
            float acc = b3[o];
            for (int j = 0; j < 256; ++j)
                acc = fmaf(h2[r][j], W3[(size_t)j * NREL + o], acc);
            out[(size_t)(p0 + r) * NREL + o] = acc;
        }
    }
}

extern "C" void kernel_launch(void* const* d_in, const int* in_sizes, int n_in,
                              void* d_out, int out_size, void* d_ws, size_t ws_size,
                              hipStream_t stream) {
    const float* feats  = (const float*)d_in[0];
    const int*   hboxes = (const int*)d_in[1];
    const int*   oboxes = (const int*)d_in[2];
    const float* W1     = (const float*)d_in[3];
    const float* b1     = (const float*)d_in[4];
    const float* W2     = (const float*)d_in[5];
    const float* b2     = (const float*)d_in[6];
    const float* W3     = (const float*)d_in[7];
    const float* b3     = (const float*)d_in[8];
    float* out = (float*)d_out;

    float* X  = (float*)d_ws;                       // 384 x 768
    float* AB = X + (size_t)384 * 768;              // 384 x 512

    roi_kernel<<<dim3(BB * (NHh + NOo)), dim3(256), 0, stream>>>(feats, hboxes, oboxes, X);
    gemm1_kernel<<<dim3(96), dim3(256), 0, stream>>>(X, W1, AB);
    mlp_kernel<<<dim3(256), dim3(256), 0, stream>>>(AB, b1, W2, b2, W3, b3, out);
}

// Round 5
// 94.503 us; speedup vs baseline: 1.6529x; 1.6529x over previous
//
#include <hip/hip_runtime.h>

#define BB   16
#define HH   74
#define WW   74
#define DD   768
#define NHh  8
#define NOo  16
#define NREL 117

// K1: ROI mean, one block per box, 768 threads:
//   g  = t/192  : row-group (rows y1+g, y1+g+4, ...)
//   c4 = t%192  : float4 channel chunk (192*4 = 768 channels)
// Output X: 384 rows x 768 (rows 0..127 = hf[b*8+h], rows 128..383 = of[b*16+o]).
__global__ __launch_bounds__(768) void roi_kernel(const float* __restrict__ feats,
                                                  const int* __restrict__ hboxes,
                                                  const int* __restrict__ oboxes,
                                                  float* __restrict__ X)
{
    __shared__ float4 part[4][192];
    int blk = blockIdx.x;
    int b = blk / (NHh + NOo);
    int i = blk % (NHh + NOo);
    const int* box;
    float* outRow;
    if (i < NHh) {
        box = hboxes + (b * NHh + i) * 4;
        outRow = X + (size_t)(b * NHh + i) * DD;
    } else {
        int o = i - NHh;
        box = oboxes + (b * NOo + o) * 4;
        outRow = X + (size_t)(128 + b * NOo + o) * DD;
    }
    int x1 = box[0], y1 = box[1], x2 = box[2], y2 = box[3];
    float inv_area = 1.0f / (float)((y2 - y1) * (x2 - x1));

    int t = threadIdx.x;
    int g = t / 192;
    int c4 = t - g * 192;

    float4 a0 = make_float4(0.f, 0.f, 0.f, 0.f);
    float4 a1 = make_float4(0.f, 0.f, 0.f, 0.f);
    for (int y = y1 + g; y < y2; y += 4) {
        const float4* rp = (const float4*)(feats + (size_t)((b * HH + y) * WW) * DD) + c4;
        int x = x1;
        for (; x + 1 < x2; x += 2) {
            float4 v0 = rp[(size_t)x * 192];
            float4 v1 = rp[(size_t)(x + 1) * 192];
            a0.x += v0.x; a0.y += v0.y; a0.z += v0.z; a0.w += v0.w;
            a1.x += v1.x; a1.y += v1.y; a1.z += v1.z; a1.w += v1.w;
        }
        if (x < x2) {
            float4 v0 = rp[(size_t)x * 192];
            a0.x += v0.x; a0.y += v0.y; a0.z += v0.z; a0.w += v0.w;
        }
    }
    a0.x += a1.x; a0.y += a1.y; a0.z += a1.z; a0.w += a1.w;
    part[g][c4] = a0;
    __syncthreads();
    if (g == 0) {
        float4 p1 = part[1][c4];
        float4 p2 = part[2][c4];
        float4 p3 = part[3][c4];
        a0.x = (a0.x + p1.x + p2.x + p3.x) * inv_area;
        a0.y = (a0.y + p1.y + p2.y + p3.y) * inv_area;
        a0.z = (a0.z + p1.z + p2.z + p3.z) * inv_area;
        a0.w = (a0.w + p1.w + p2.w + p3.w) * inv_area;
        ((float4*)outRow)[c4] = a0;
    }
}

// K2: partial GEMM.  grid = (96, 2): x = 4-row group, y = k-half (384 of 768).
// 512 threads, thread t owns output column t.  Rows <128 use W1[0:768,:],
// rows >=128 use W1[768:1536,:]; k-half kh covers W1 rows [kh*384, kh*384+384).
__global__ __launch_bounds__(512) void gemm1_kernel(const float* __restrict__ X,
                                                    const float* __restrict__ W1,
                                                    float* __restrict__ AB0,
                                                    float* __restrict__ AB1)
{
    __shared__ float xs[4][384];
    int r0 = blockIdx.x * 4;
    int kh = blockIdx.y;
    int k0 = kh * 384;
    int t = threadIdx.x;
    for (int idx = t; idx < 4 * 384; idx += 512) {
        int r = idx / 384;
        int k = idx - r * 384;
        xs[r][k] = X[(size_t)(r0 + r) * DD + k0 + k];
    }
    __syncthreads();
    const float* Wp = W1 + ((r0 < 128) ? 0 : (size_t)DD * 512) + (size_t)k0 * 512;
    float acc[4] = {};
    for (int kk = 0; kk < 384; ++kk) {
        float w = Wp[(size_t)kk * 512 + t];
#pragma unroll
        for (int r = 0; r < 4; ++r) acc[r] = fmaf(xs[r][kk], w, acc[r]);
    }
    float* ABp = kh ? AB1 : AB0;
    for (int r = 0; r < 4; ++r) ABp[(size_t)(r0 + r) * 512 + t] = acc[r];
}

// K3: fused pair-combine + layer2 + layer3.  8 pair-rows per block,
// 512 threads, grid = 256 blocks.
__global__ __launch_bounds__(512) void mlp_kernel(const float* __restrict__ AB0,
                                                  const float* __restrict__ AB1,
                                                  const float* __restrict__ b1,
                                                  const float* __restrict__ W2,
                                                  const float* __restrict__ b2,
                                                  const float* __restrict__ W3,
                                                  const float* __restrict__ b3,
                                                  float* __restrict__ out)
{
    __shared__ float h1[8][512];
    __shared__ float h2[8][256];
    int p0 = blockIdx.x * 8;
    int t = threadIdx.x;

    // phase 1: h1 = relu(A_row + B_row + b1), summing the two k-partials
    for (int idx = t; idx < 8 * 512; idx += 512) {
        int r = idx >> 9;
        int k = idx & 511;
        int p = p0 + r;
        int rowA = p >> 4;                          // b*8 + h
        int rowB = 128 + (p >> 7) * 16 + (p & 15);  // 128 + b*16 + o
        float v = AB0[(size_t)rowA * 512 + k] + AB1[(size_t)rowA * 512 + k]
                + AB0[(size_t)rowB * 512 + k] + AB1[(size_t)rowB * 512 + k] + b1[k];
        h1[r][k] = v > 0.f ? v : 0.f;
    }
    __syncthreads();

    // phase 2: h2 = relu(h1 @ W2 + b2).  j = t&255 is the output column,
    // rh = t>>8 picks rows 0-3 / 4-7 (wave-uniform -> h1 reads broadcast).
    {
        int j = t & 255;
        int rh = t >> 8;
        float acc[4] = {};
        for (int k = 0; k < 512; ++k) {
            float w = W2[(size_t)k * 256 + j];
#pragma unroll
            for (int rr = 0; rr < 4; ++rr) acc[rr] = fmaf(h1[rh * 4 + rr][k], w, acc[rr]);
        }
        float bb = b2[j];
#pragma unroll
        for (int rr = 0; rr < 4; ++rr) {
            float v = acc[rr] + bb;
            h2[rh * 4 + rr][j] = v > 0.f ? v : 0.f;
        }
    }
    __syncthreads();

    // phase 3: out = h2 @ W3 + b3  (8 rows x 117 outputs = 936; 512 threads
    // -> 2 iterations to cover all 936 slots)
#pragma unroll
    for (int it = 0; it < 2; ++it) {
        int pidx = t + it * 512;
        if (pidx < 8 * NREL) {
            int r = pidx / NREL;
            int o = pidx - r * NREL;
            float acc = b3[o];
            for (int j = 0; j < 256; ++j)
                acc = fmaf(h2[r][j], W3[(size_t)j * NREL + o], acc);
            out[(size_t)(p0 + r) * NREL + o] = acc;
        }
    }
}

extern "C" void kernel_launch(void* const* d_in, const int* in_sizes, int n_in,
                              void* d_out, int out_size, void* d_ws, size_t ws_size,
                              hipStream_t stream) {
    const float* feats  = (const float*)d_in[0];
    const int*   hboxes = (const int*)d_in[1];
    const int*   oboxes = (const int*)d_in[2];
    const float* W1     = (const float*)d_in[3];
    const float* b1     = (const float*)d_in[4];
    const float* W2     = (const float*)d_in[5];
    const float* b2     = (const float*)d_in[6];
    const float* W3     = (const float*)d_in[7];
    const float* b3     = (const float*)d_in[8];
    float* out = (float*)d_out;

    float* X   = (float*)d_ws;                      // 384 x 768
    float* AB0 = X + (size_t)384 * DD;              // 384 x 512
    float* AB1 = AB0 + (size_t)384 * 512;           // 384 x 512

    roi_kernel<<<dim3(BB * (NHh + NOo)), dim3(768), 0, stream>>>(feats, hboxes, oboxes, X);
    gemm1_kernel<<<dim3(96, 2), dim3(512), 0, stream>>>(X, W1, AB0, AB1);
    mlp_kernel<<<dim3(256), dim3(512), 0, stream>>>(AB0, AB1, b1, W2, b2, W3, b3, out);
}